// Round 14
// baseline (67.458 us; speedup 1.0000x reference)
//
#include <hip/hip_runtime.h>
#include <math.h>

#define SR      44100.0
#define T_LEN   441000
#define B_ROWS  32
#define NCH     13782            // chunks per row (32 samples each; last = 8)
#define GCH     (B_ROWS * NCH)
#define BPR     54               // blocks per row (256 chunks per block)
#define NBLK    (B_ROWS * BPR)   // 1728
#define NMAT    14               // W^(2^k), k=0..13  (W = A^32; B = W^256 = k=8)

// ws layout (floats)
#define WS_MAT  0                // 14*36 = 504
#define WS_AG   512              // NBLK*6 block aggregates
#define WS_F    21248            // GCH*6: relative entries (written by kA)

typedef __attribute__((address_space(1))) const void gconst_t;
typedef __attribute__((address_space(3))) void lds_t;
#define GL2LDS(gp, lp) __builtin_amdgcn_global_load_lds((gconst_t*)(gp), (lds_t*)(lp), 16, 0, 0)

// ---------------- shared helpers (verified rounds 3..13) ----------------

#define COMPUTE_COEFS(scoef, dco, qs, gains) do { \
    if (threadIdx.x < 3) { \
      int f = threadIdx.x; \
      double cfq = 100.0 * exp(log(30.0) * (double)f / 3.0); \
      double w0 = 2.0 * M_PI * cfq / SR; \
      double alpha = sin(w0) / (2.0 * (double)qs[f]); \
      double Ag = exp((double)gains[f] * (2.302585092994045684 / 40.0)); \
      double a0 = 1.0 + alpha / Ag; \
      double c0 = (1.0 + alpha * Ag) / a0; \
      double c1 = (-2.0 * cos(w0)) / a0; \
      double c2 = (1.0 - alpha * Ag) / a0; \
      double c3 = c1; \
      double c4 = (1.0 - alpha / Ag) / a0; \
      dco[f*5+0]=c0; dco[f*5+1]=c1; dco[f*5+2]=c2; dco[f*5+3]=c3; dco[f*5+4]=c4; \
      scoef[f*5+0]=(float)c0; scoef[f*5+1]=(float)c1; scoef[f*5+2]=(float)c2; \
      scoef[f*5+3]=(float)c3; scoef[f*5+4]=(float)c4; \
    } \
  } while (0)

#define LOAD_COEFS(cf) \
  const float b00=cf[0],b10=cf[1],b20=cf[2],a10=cf[3],a20=cf[4]; \
  const float b01=cf[5],b11=cf[6],b21=cf[7],a11=cf[8],a21=cf[9]; \
  const float b02=cf[10],b12=cf[11],b22=cf[12],a12=cf[13],a22=cf[14];

#define CASCADE_STEP(xx) do { \
    float y1 = fmaf(b00, (xx), s11); \
    s11 = fmaf(-a10, y1, fmaf(b10, (xx), s21)); \
    s21 = fmaf(-a20, y1, b20 * (xx)); \
    float y2 = fmaf(b01, y1, s12); \
    s12 = fmaf(-a11, y2, fmaf(b11, y1, s22)); \
    s22 = fmaf(-a21, y2, b21 * y1); \
    y3 = fmaf(b02, y2, s13); \
    s13 = fmaf(-a12, y3, fmaf(b12, y2, s23)); \
    s23 = fmaf(-a22, y3, b22 * y2); \
  } while (0)

#define MV6(dst, M, v, add) do { \
    _Pragma("unroll") \
    for (int _i = 0; _i < 6; _i++) { \
      float _s = (add)[_i]; \
      _Pragma("unroll") \
      for (int _k = 0; _k < 6; _k++) _s = fmaf((M)[_i*6+_k], (v)[_k], _s); \
      (dst)[_i] = _s; \
    } \
  } while (0)

__device__ __forceinline__ void mm6d(const double* X, const double* Y, double* Z, int t) {
  if (t < 36) {
    int i = t / 6, j = t % 6;
    double s = 0.0;
    #pragma unroll
    for (int k = 0; k < 6; k++) s += X[i*6+k] * Y[k*6+j];
    Z[t] = s;
  }
}

// Staging swizzle: LDS float4-slot s holds global float4 g(s)=(s&~7)|((s&7)^((s>>3)&7)).
// Involution, line-local (coalescing intact), ds_read_b128 bank-balanced.

#define STAGE_AUDIO() do { \
    if (span4 == 512) { \
      _Pragma("unroll") \
      for (int i = 0; i < 8; i++) { \
        int s = (i << 6) + lane; \
        int g = (s & ~7) | ((s & 7) ^ ((s >> 3) & 7)); \
        GL2LDS(xp + g, slab + (i << 8)); \
      } \
    } else { \
      _Pragma("unroll") \
      for (int i = 0; i < 8; i++) { \
        int s = (i << 6) + lane; \
        int g = (s & ~7) | ((s & 7) ^ ((s >> 3) & 7)); \
        if (g < span4) GL2LDS(xp + g, slab + (i << 8)); \
      } \
    } \
  } while (0)

// ---------------- kA: finals + in-block LDS scan -> relative entries + aggregates ----------------
// (byte-identical to round 13's kA, verified 60.8us total)

__global__ __launch_bounds__(256) void kA_scan(const float* __restrict__ x,
                                               const float* __restrict__ qs,
                                               const float* __restrict__ gains,
                                               float* __restrict__ ws) {
  __shared__ __align__(16) float lds[4 * 2048];   // audio slabs; later scan ping-pong bufs
  __shared__ double Da[36], Db[36];
  __shared__ double dco[15];
  __shared__ float sVm[8][36];                    // W^(2^k), k=0..7 (scan uses k=0..6)
  __shared__ float scoef[16];
  const int tid = threadIdx.x;
  const int wib = tid >> 6, lane = tid & 63;
  const int b = blockIdx.x;
  const int row = b / BPR, jb = b - row * BPR;
  const int wci = (jb << 2) + wib;
  long rowbase = (long)row * T_LEN;
  int s0 = wci << 11;
  int span4 = (min(2048, T_LEN - s0)) >> 2;        // 512, or 170 for last wave of row
  const float4* xp = (const float4*)(x + rowbase + s0);
  float* slab = lds + (wib << 11);
  STAGE_AUDIO();
  COMPUTE_COEFS(scoef, dco, qs, gains);
  // wave 0 only: matrix chain (DS ops in-order within a wave; no block barriers)
  if (wib == 0) {
    if (lane == 0) {
      double u[7] = {0,0,0,0,0,0,1};   // current filter input as linear form over (S, x)
      for (int f = 0; f < 3; f++) {
        double c0=dco[f*5+0], c1=dco[f*5+1], c2=dco[f*5+2], c3=dco[f*5+3], c4=dco[f*5+4];
        double yv[7], s1p[7], s2p[7];
        for (int i = 0; i < 7; i++) {
          yv[i]  = c0 * u[i] + ((i == 2*f)   ? 1.0 : 0.0);
          s1p[i] = c1 * u[i] + ((i == 2*f+1) ? 1.0 : 0.0) - c3 * yv[i];
          s2p[i] = c2 * u[i] - c4 * yv[i];
        }
        for (int i = 0; i < 6; i++) { Da[(2*f)*6+i] = s1p[i]; Da[(2*f+1)*6+i] = s2p[i]; }
        for (int i = 0; i < 7; i++) u[i] = yv[i];
      }
    }
    double* cur = Da; double* oth = Db;
    #pragma unroll
    for (int s = 0; s < 5; s++) {                  // A -> A^32 = W
      mm6d(cur, cur, oth, lane);
      double* tm = cur; cur = oth; oth = tm;
    }
    #pragma unroll
    for (int k = 0; k < NMAT; k++) {               // publish W^(2^k)
      if (lane < 36) {
        float wv = (float)cur[lane];
        if (k < 8) sVm[k][lane] = wv;
        if (b == 0) ws[WS_MAT + k*36 + lane] = wv;
      }
      if (k < NMAT - 1) {
        mm6d(cur, cur, oth, lane);
        double* tm = cur; cur = oth; oth = tm;
      }
    }
  }
  __syncthreads();

  // cascade over own chunk (32 samples) from zero state
  int ci = (jb << 8) + tid;                        // chunk index within row
  bool valid = ci < NCH;
  float f6[6] = {0,0,0,0,0,0};
  if (valid) {
    LOAD_COEFS(scoef);
    int n4 = (ci == NCH - 1) ? 2 : 8;
    const float* rowp = slab + (lane << 5);
    int xr = lane & 7;
    float s11=0,s21=0,s12=0,s22=0,s13=0,s23=0, y3;
    if (n4 == 8) {
      #pragma unroll
      for (int j4 = 0; j4 < 8; j4++) {
        float4 v = *(const float4*)(rowp + ((j4 ^ xr) << 2));
        CASCADE_STEP(v.x); CASCADE_STEP(v.y); CASCADE_STEP(v.z); CASCADE_STEP(v.w);
      }
    } else {
      for (int j4 = 0; j4 < 2; j4++) {
        float4 v = *(const float4*)(rowp + ((j4 ^ xr) << 2));
        CASCADE_STEP(v.x); CASCADE_STEP(v.y); CASCADE_STEP(v.z); CASCADE_STEP(v.w);
      }
    }
    (void)y3;
    f6[0]=s11; f6[1]=s21; f6[2]=s12; f6[3]=s22; f6[4]=s13; f6[5]=s23;
  }
  __syncthreads();                                 // slab reads complete; reuse as scan bufs

  // in-block Hillis-Steele, rounds k=0..5 (window 64); remaining distance folded
  // into the exclusive read via nested W^64 terms (verified r13).
  float* src = lds;          // 256*7 floats
  float* dst = lds + 1792;   // 256*7 floats
  #pragma unroll
  for (int i = 0; i < 6; i++) src[tid*7 + i] = f6[i];
  __syncthreads();
  for (int k = 0; k < 6; k++) {
    int d = 1 << k;
    float nv[6];
    if (tid >= d) { MV6(nv, sVm[k], src + (tid-d)*7, src + tid*7); }
    else {
      #pragma unroll
      for (int i = 0; i < 6; i++) nv[i] = src[tid*7 + i];
    }
    #pragma unroll
    for (int i = 0; i < 6; i++) dst[tid*7 + i] = nv[i];
    __syncthreads();
    float* tm = src; src = dst; dst = tm;
  }
  // src holds H[t] = fold over window (t-63..t).
  // E[t] = H[t-1] + W64*(H[t-65] + W64*(H[t-129] + W64*H[t-193]))  (terms while idx>=0)
  if (valid) {
    float e[6];
    if (tid == 0) {
      #pragma unroll
      for (int i = 0; i < 6; i++) e[i] = 0.0f;
    } else if (tid <= 64) {
      #pragma unroll
      for (int i = 0; i < 6; i++) e[i] = src[(tid-1)*7 + i];
    } else {
      float acc[6];
      if (tid <= 128) {
        #pragma unroll
        for (int i = 0; i < 6; i++) acc[i] = src[(tid-65)*7 + i];
      } else {
        float acc2[6];
        if (tid <= 192) {
          #pragma unroll
          for (int i = 0; i < 6; i++) acc2[i] = src[(tid-129)*7 + i];
        } else {
          MV6(acc2, sVm[6], src + (tid-193)*7, src + (tid-129)*7);
        }
        MV6(acc, sVm[6], acc2, src + (tid-65)*7);
      }
      MV6(e, sVm[6], acc, src + (tid-1)*7);
    }
    float2* E = (float2*)(ws + WS_F + ((long)row * NCH + ci) * 6);
    E[0] = make_float2(e[0], e[1]); E[1] = make_float2(e[2], e[3]); E[2] = make_float2(e[4], e[5]);
  }
  // block aggregate: state after all 256 chunks (nested W64 folds) — consumed for jb < 53
  if (tid == 255 && jb < BPR - 1) {
    float a1[6], a2[6], g6[6];
    MV6(a1, sVm[6], src + 63*7, src + 127*7);      // state 0..127
    MV6(a2, sVm[6], a1, src + 191*7);              // state 0..191
    MV6(g6, sVm[6], a2, src + 255*7);              // state 0..255
    #pragma unroll
    for (int i = 0; i < 6; i++) ws[WS_AG + ((long)row * BPR + jb) * 6 + i] = g6[i];
  }
}

// ---------------- kC: overlapped wave0 row-scan (2 barriers) + absolutize + emit ----------------

__global__ __launch_bounds__(256) void kC_emit(const float* __restrict__ x,
                                               const float* __restrict__ qs,
                                               const float* __restrict__ gains,
                                               float* __restrict__ y,
                                               const float* __restrict__ ws) {
  __shared__ __align__(16) float lds[4 * 2048];
  __shared__ float smat[8 * 36];                  // W^(2^k), k=0..7 (absolutize)
  __shared__ float sB[6 * 36];                    // B^(2^k), k=0..5 (wave0 row scan)
  __shared__ float scoef[16];
  __shared__ double dco[15];
  __shared__ float sO[6];
  const int tid = threadIdx.x;
  const int wib = tid >> 6, lane = tid & 63;
  const int b = blockIdx.x;
  const int row = b / BPR, jb = b - row * BPR;
  const int wci = (jb << 2) + wib;
  long rowbase = (long)row * T_LEN;
  int s0 = wci << 11;
  int span4 = (min(2048, T_LEN - s0)) >> 2;
  const float4* xp = (const float4*)(x + rowbase + s0);
  float* slab = lds + (wib << 11);
  STAGE_AUDIO();
  // coop-load absolutize matrices (consumed only after the barrier)
  for (int i = tid; i < 8 * 36; i += 256) smat[i] = ws[WS_MAT + i];
  COMPUTE_COEFS(scoef, dco, qs, gains);
  // per-thread relative entry loads into regs (compiler tracks the wait)
  int ci = (jb << 8) + tid;
  bool valid = ci < NCH;
  float e0=0,e1v=0,e2=0,e3=0,e4=0,e5=0;
  if (valid) {
    const float2* E = (const float2*)(ws + WS_F + ((long)row * NCH + ci) * 6);
    float2 p0 = E[0], p1 = E[1], p2 = E[2];
    e0=p0.x; e1v=p0.y; e2=p1.x; e3=p1.y; e4=p2.x; e5=p2.y;
  }
  // wave 0: self-load B matrices (wave-local LDS, in-order within the wave), then
  // run the row-offset scan concurrently with other waves' staging (r12-verified).
  if (wib == 0) {
    for (int i = lane; i < 6 * 36; i += 64) sB[i] = ws[WS_MAT + 8 * 36 + i];
    float ag[6] = {0,0,0,0,0,0};
    if (lane < BPR - 1) {
      const float* p = ws + WS_AG + ((long)row * BPR + lane) * 6;
      #pragma unroll
      for (int i = 0; i < 6; i++) ag[i] = p[i];
    }
    if (jb == 0) {
      if (lane == 0) {
        #pragma unroll
        for (int i = 0; i < 6; i++) sO[i] = 0.0f;
      }
    } else {
      float v6s[6];
      #pragma unroll
      for (int i = 0; i < 6; i++) v6s[i] = ag[i];
      #pragma unroll
      for (int k = 0; k < 6; k++) {
        int d = 1 << k;
        float u[6];
        #pragma unroll
        for (int i = 0; i < 6; i++) u[i] = __shfl_up(v6s[i], d, 64);
        float nv[6];
        MV6(nv, sB + k * 36, u, v6s);              // B^(2^k), B = W^256
        #pragma unroll
        for (int i = 0; i < 6; i++) v6s[i] = (lane >= d) ? nv[i] : v6s[i];
      }
      if (lane == jb - 1) {
        #pragma unroll
        for (int i = 0; i < 6; i++) sO[i] = v6s[i];
      }
    }
  }
  __syncthreads();                                 // sO + smat + all slabs resident

  if (valid) {
    LOAD_COEFS(scoef);
    // absolute entry = rel_entry + W^tid * O_block
    float m[6];
    #pragma unroll
    for (int i = 0; i < 6; i++) m[i] = sO[i];
    float z6[6] = {0,0,0,0,0,0};
    #pragma unroll
    for (int k = 0; k < 8; k++) {
      if ((tid >> k) & 1) {
        float nm[6];
        MV6(nm, smat + k*36, m, z6);
        #pragma unroll
        for (int i = 0; i < 6; i++) m[i] = nm[i];
      }
    }
    float s11=e0+m[0], s21=e1v+m[1], s12=e2+m[2], s22=e3+m[3], s13=e4+m[4], s23=e5+m[5];
    int n4 = (ci == NCH - 1) ? 2 : 8;
    float* rowp = slab + (lane << 5);
    int xr = lane & 7;
    float y3;
    if (n4 == 8) {
      #pragma unroll
      for (int j4 = 0; j4 < 8; j4++) {
        float* p = rowp + ((j4 ^ xr) << 2);
        float4 v = *(const float4*)p;
        float4 o;
        CASCADE_STEP(v.x); o.x = y3;
        CASCADE_STEP(v.y); o.y = y3;
        CASCADE_STEP(v.z); o.z = y3;
        CASCADE_STEP(v.w); o.w = y3;
        *(float4*)p = o;
      }
    } else {
      for (int j4 = 0; j4 < 2; j4++) {
        float* p = rowp + ((j4 ^ xr) << 2);
        float4 v = *(const float4*)p;
        float4 o;
        CASCADE_STEP(v.x); o.x = y3;
        CASCADE_STEP(v.y); o.y = y3;
        CASCADE_STEP(v.z); o.z = y3;
        CASCADE_STEP(v.w); o.w = y3;
        *(float4*)p = o;
      }
    }
  }
  __syncthreads();                                 // all emits done before coop store
  float4* yp = (float4*)(y + rowbase + s0);
  if (span4 == 512) {
    #pragma unroll
    for (int i = 0; i < 8; i++) {
      int g = (i << 6) + lane;
      int s = (g & ~7) | ((g & 7) ^ ((g >> 3) & 7));
      yp[g] = *(const float4*)(slab + (s << 2));
    }
  } else {
    #pragma unroll
    for (int i = 0; i < 8; i++) {
      int g = (i << 6) + lane;
      int s = (g & ~7) | ((g & 7) ^ ((g >> 3) & 7));
      if (g < span4) yp[g] = *(const float4*)(slab + (s << 2));
    }
  }
}

extern "C" void kernel_launch(void* const* d_in, const int* in_sizes, int n_in,
                              void* d_out, int out_size, void* d_ws, size_t ws_size,
                              hipStream_t stream) {
  const float* audio = (const float*)d_in[0];
  const float* qs    = (const float*)d_in[1];
  const float* gains = (const float*)d_in[2];
  float* out = (float*)d_out;
  float* ws  = (float*)d_ws;

  hipLaunchKernelGGL(kA_scan, dim3(NBLK), dim3(256), 0, stream, audio, qs, gains, ws);
  hipLaunchKernelGGL(kC_emit, dim3(NBLK), dim3(256), 0, stream, audio, qs, gains, out, ws);
}

// Round 15
// 58.552 us; speedup vs baseline: 1.1521x; 1.1521x over previous
//
#include <hip/hip_runtime.h>
#include <math.h>

#define SR      44100.0
#define T_LEN   441000
#define B_ROWS  32
#define NCH     13782            // chunks per row (32 samples each; last = 8)
#define GCH     (B_ROWS * NCH)
#define BPR     54               // blocks per row (256 chunks per block)
#define NBLK    (B_ROWS * BPR)   // 1728
#define NMAT    14               // W^(2^k), k=0..13  (W = A^32; B = W^256 = k=8)

// ws layout (floats)
#define WS_MAT  0                // 14*36 = 504
#define WS_AG   512              // NBLK*6 block aggregates
#define WS_F    21248            // GCH*6: relative entries (written by kA)

typedef __attribute__((address_space(1))) const void gconst_t;
typedef __attribute__((address_space(3))) void lds_t;
#define GL2LDS(gp, lp) __builtin_amdgcn_global_load_lds((gconst_t*)(gp), (lds_t*)(lp), 16, 0, 0)

// ---------------- shared helpers (verified rounds 3..13) ----------------

// classic single-copy coefs (kC, verified r11)
#define COMPUTE_COEFS(scoef, dco, qs, gains) do { \
    if (threadIdx.x < 3) { \
      int f = threadIdx.x; \
      double cfq = 100.0 * exp(log(30.0) * (double)f / 3.0); \
      double w0 = 2.0 * M_PI * cfq / SR; \
      double alpha = sin(w0) / (2.0 * (double)qs[f]); \
      double Ag = exp((double)gains[f] * (2.302585092994045684 / 40.0)); \
      double a0 = 1.0 + alpha / Ag; \
      double c0 = (1.0 + alpha * Ag) / a0; \
      double c1 = (-2.0 * cos(w0)) / a0; \
      double c2 = (1.0 - alpha * Ag) / a0; \
      double c3 = c1; \
      double c4 = (1.0 - alpha / Ag) / a0; \
      dco[f*5+0]=c0; dco[f*5+1]=c1; dco[f*5+2]=c2; dco[f*5+3]=c3; dco[f*5+4]=c4; \
      scoef[f*5+0]=(float)c0; scoef[f*5+1]=(float)c1; scoef[f*5+2]=(float)c2; \
      scoef[f*5+3]=(float)c3; scoef[f*5+4]=(float)c4; \
    } \
  } while (0)

// per-wave coefs (kA): lanes 0..2 of EACH wave fill wave-private slot; wave 0 also dco
#define COMPUTE_COEFS_PW(scoef4, dco) do { \
    if (lane < 3) { \
      int f = lane; \
      double cfq = 100.0 * exp(log(30.0) * (double)f / 3.0); \
      double w0 = 2.0 * M_PI * cfq / SR; \
      double alpha = sin(w0) / (2.0 * (double)qs[f]); \
      double Ag = exp((double)gains[f] * (2.302585092994045684 / 40.0)); \
      double a0 = 1.0 + alpha / Ag; \
      double c0 = (1.0 + alpha * Ag) / a0; \
      double c1 = (-2.0 * cos(w0)) / a0; \
      double c2 = (1.0 - alpha * Ag) / a0; \
      double c3 = c1; \
      double c4 = (1.0 - alpha / Ag) / a0; \
      if (wib == 0) { dco[f*5+0]=c0; dco[f*5+1]=c1; dco[f*5+2]=c2; dco[f*5+3]=c3; dco[f*5+4]=c4; } \
      float* _sc = (scoef4) + (wib << 4); \
      _sc[f*5+0]=(float)c0; _sc[f*5+1]=(float)c1; _sc[f*5+2]=(float)c2; \
      _sc[f*5+3]=(float)c3; _sc[f*5+4]=(float)c4; \
    } \
  } while (0)

#define LOAD_COEFS(cf) \
  const float b00=cf[0],b10=cf[1],b20=cf[2],a10=cf[3],a20=cf[4]; \
  const float b01=cf[5],b11=cf[6],b21=cf[7],a11=cf[8],a21=cf[9]; \
  const float b02=cf[10],b12=cf[11],b22=cf[12],a12=cf[13],a22=cf[14];

#define CASCADE_STEP(xx) do { \
    float y1 = fmaf(b00, (xx), s11); \
    s11 = fmaf(-a10, y1, fmaf(b10, (xx), s21)); \
    s21 = fmaf(-a20, y1, b20 * (xx)); \
    float y2 = fmaf(b01, y1, s12); \
    s12 = fmaf(-a11, y2, fmaf(b11, y1, s22)); \
    s22 = fmaf(-a21, y2, b21 * y1); \
    y3 = fmaf(b02, y2, s13); \
    s13 = fmaf(-a12, y3, fmaf(b12, y2, s23)); \
    s23 = fmaf(-a22, y3, b22 * y2); \
  } while (0)

#define MV6(dst, M, v, add) do { \
    _Pragma("unroll") \
    for (int _i = 0; _i < 6; _i++) { \
      float _s = (add)[_i]; \
      _Pragma("unroll") \
      for (int _k = 0; _k < 6; _k++) _s = fmaf((M)[_i*6+_k], (v)[_k], _s); \
      (dst)[_i] = _s; \
    } \
  } while (0)

__device__ __forceinline__ void mm6d(const double* X, const double* Y, double* Z, int t) {
  if (t < 36) {
    int i = t / 6, j = t % 6;
    double s = 0.0;
    #pragma unroll
    for (int k = 0; k < 6; k++) s += X[i*6+k] * Y[k*6+j];
    Z[t] = s;
  }
}

// Staging swizzle: LDS float4-slot s holds global float4 g(s)=(s&~7)|((s&7)^((s>>3)&7)).
// Involution, line-local (coalescing intact), ds_read_b128 bank-balanced.

#define STAGE_AUDIO() do { \
    if (span4 == 512) { \
      _Pragma("unroll") \
      for (int i = 0; i < 8; i++) { \
        int s = (i << 6) + lane; \
        int g = (s & ~7) | ((s & 7) ^ ((s >> 3) & 7)); \
        GL2LDS(xp + g, slab + (i << 8)); \
      } \
    } else { \
      _Pragma("unroll") \
      for (int i = 0; i < 8; i++) { \
        int s = (i << 6) + lane; \
        int g = (s & ~7) | ((s & 7) ^ ((s >> 3) & 7)); \
        if (g < span4) GL2LDS(xp + g, slab + (i << 8)); \
      } \
    } \
  } while (0)

// ---------------- kA: finals + in-block LDS scan -> relative entries + aggregates ----------------
// r11 kA + (1) per-wave coefs, (2) first barrier -> per-wave vmcnt(0), (3) chain k<8 for b>0.

__global__ __launch_bounds__(256) void kA_scan(const float* __restrict__ x,
                                               const float* __restrict__ qs,
                                               const float* __restrict__ gains,
                                               float* __restrict__ ws) {
  __shared__ __align__(16) float lds[4 * 2048];   // audio slabs; later scan ping-pong bufs
  __shared__ double Da[36], Db[36];
  __shared__ double dco[15];
  __shared__ float sVm[8][36];                    // W^(2^k), k=0..7
  __shared__ float scoef4[64];                    // per-wave coef copies (16 floats each)
  const int tid = threadIdx.x;
  const int wib = tid >> 6, lane = tid & 63;
  const int b = blockIdx.x;
  const int row = b / BPR, jb = b - row * BPR;
  const int wci = (jb << 2) + wib;
  long rowbase = (long)row * T_LEN;
  int s0 = wci << 11;
  int span4 = (min(2048, T_LEN - s0)) >> 2;        // 512, or 170 for last wave of row
  const float4* xp = (const float4*)(x + rowbase + s0);
  float* slab = lds + (wib << 11);
  STAGE_AUDIO();
  COMPUTE_COEFS_PW(scoef4, dco);
  // wave 0 only: matrix chain (wave-internal DS ordering; no block barrier needed —
  // sVm consumers sit behind the post-cascade barrier, which wave 0 reaches last)
  if (wib == 0) {
    if (lane == 0) {
      double u[7] = {0,0,0,0,0,0,1};   // current filter input as linear form over (S, x)
      for (int f = 0; f < 3; f++) {
        double c0=dco[f*5+0], c1=dco[f*5+1], c2=dco[f*5+2], c3=dco[f*5+3], c4=dco[f*5+4];
        double yv[7], s1p[7], s2p[7];
        for (int i = 0; i < 7; i++) {
          yv[i]  = c0 * u[i] + ((i == 2*f)   ? 1.0 : 0.0);
          s1p[i] = c1 * u[i] + ((i == 2*f+1) ? 1.0 : 0.0) - c3 * yv[i];
          s2p[i] = c2 * u[i] - c4 * yv[i];
        }
        for (int i = 0; i < 6; i++) { Da[(2*f)*6+i] = s1p[i]; Da[(2*f+1)*6+i] = s2p[i]; }
        for (int i = 0; i < 7; i++) u[i] = yv[i];
      }
    }
    double* cur = Da; double* oth = Db;
    #pragma unroll
    for (int s = 0; s < 5; s++) {                  // A -> A^32 = W
      mm6d(cur, cur, oth, lane);
      double* tm = cur; cur = oth; oth = tm;
    }
    const int kmax = (b == 0) ? NMAT : 8;          // only block 0 needs k=8..13
    for (int k = 0; k < kmax; k++) {               // publish W^(2^k)
      if (lane < 36) {
        float wv = (float)cur[lane];
        if (k < 8) sVm[k][lane] = wv;
        if (b == 0) ws[WS_MAT + k*36 + lane] = wv;
      }
      if (k < kmax - 1) {
        mm6d(cur, cur, oth, lane);
        double* tm = cur; cur = oth; oth = tm;
      }
    }
  }
  // per-wave: wait for this wave's own global_load_lds, then cascade (wave-local slab)
  asm volatile("s_waitcnt vmcnt(0)" ::: "memory");

  int ci = (jb << 8) + tid;                        // chunk index within row
  bool valid = ci < NCH;
  float f6[6] = {0,0,0,0,0,0};
  if (valid) {
    const float* cf = scoef4 + (wib << 4);
    LOAD_COEFS(cf);
    int n4 = (ci == NCH - 1) ? 2 : 8;
    const float* rowp = slab + (lane << 5);
    int xr = lane & 7;
    float s11=0,s21=0,s12=0,s22=0,s13=0,s23=0, y3;
    if (n4 == 8) {
      #pragma unroll
      for (int j4 = 0; j4 < 8; j4++) {
        float4 v = *(const float4*)(rowp + ((j4 ^ xr) << 2));
        CASCADE_STEP(v.x); CASCADE_STEP(v.y); CASCADE_STEP(v.z); CASCADE_STEP(v.w);
      }
    } else {
      for (int j4 = 0; j4 < 2; j4++) {
        float4 v = *(const float4*)(rowp + ((j4 ^ xr) << 2));
        CASCADE_STEP(v.x); CASCADE_STEP(v.y); CASCADE_STEP(v.z); CASCADE_STEP(v.w);
      }
    }
    (void)y3;
    f6[0]=s11; f6[1]=s21; f6[2]=s12; f6[3]=s22; f6[4]=s13; f6[5]=s23;
  }
  __syncthreads();                                 // all slab reads + sVm writes complete

  // in-block Hillis-Steele over 256 chunks (items: x -> W x + f)  [r11-verified]
  float* src = lds;          // 256*7 floats
  float* dst = lds + 1792;   // 256*7 floats
  #pragma unroll
  for (int i = 0; i < 6; i++) src[tid*7 + i] = f6[i];
  __syncthreads();
  for (int k = 0; k < 8; k++) {
    int d = 1 << k;
    float nv[6];
    if (tid >= d) { MV6(nv, sVm[k], src + (tid-d)*7, src + tid*7); }
    else {
      #pragma unroll
      for (int i = 0; i < 6; i++) nv[i] = src[tid*7 + i];
    }
    #pragma unroll
    for (int i = 0; i < 6; i++) dst[tid*7 + i] = nv[i];
    __syncthreads();
    float* tm = src; src = dst; dst = tm;
  }
  // relative entry = exclusive prefix; write once (no finals to memory)
  if (valid) {
    float e[6];
    if (tid > 0) {
      #pragma unroll
      for (int i = 0; i < 6; i++) e[i] = src[(tid-1)*7 + i];
    } else {
      #pragma unroll
      for (int i = 0; i < 6; i++) e[i] = 0.0f;
    }
    float2* E = (float2*)(ws + WS_F + ((long)row * NCH + ci) * 6);
    E[0] = make_float2(e[0], e[1]); E[1] = make_float2(e[2], e[3]); E[2] = make_float2(e[4], e[5]);
  }
  // block aggregate (inclusive of all 256 chunks) — only consumed for jb < 53
  if (tid == 255 && jb < BPR - 1) {
    #pragma unroll
    for (int i = 0; i < 6; i++) ws[WS_AG + ((long)row * BPR + jb) * 6 + i] = src[255*7 + i];
  }
}

// ---------------- kC: wave0 row-offset scan + absolutize + emit (byte-identical to r11) ----------------

__global__ __launch_bounds__(256) void kC_emit(const float* __restrict__ x,
                                               const float* __restrict__ qs,
                                               const float* __restrict__ gains,
                                               float* __restrict__ y,
                                               const float* __restrict__ ws) {
  __shared__ __align__(16) float lds[4 * 2048];
  __shared__ float smat[NMAT * 36];
  __shared__ float scoef[16];
  __shared__ double dco[15];
  __shared__ float sO[6];
  const int tid = threadIdx.x;
  const int wib = tid >> 6, lane = tid & 63;
  const int b = blockIdx.x;
  const int row = b / BPR, jb = b - row * BPR;
  const int wci = (jb << 2) + wib;
  long rowbase = (long)row * T_LEN;
  int s0 = wci << 11;
  int span4 = (min(2048, T_LEN - s0)) >> 2;
  const float4* xp = (const float4*)(x + rowbase + s0);
  float* slab = lds + (wib << 11);
  STAGE_AUDIO();
  // overlap under staging: matrices, aggregates (wave0 regs), coefs, relative entries
  for (int i = tid; i < NMAT * 36; i += 256) smat[i] = ws[WS_MAT + i];
  float ag[6] = {0,0,0,0,0,0};
  if (wib == 0 && lane < BPR - 1) {
    const float* p = ws + WS_AG + ((long)row * BPR + lane) * 6;
    #pragma unroll
    for (int i = 0; i < 6; i++) ag[i] = p[i];
  }
  COMPUTE_COEFS(scoef, dco, qs, gains);
  if (tid == 0 && jb == 0) {
    #pragma unroll
    for (int i = 0; i < 6; i++) sO[i] = 0.0f;
  }
  int ci = (jb << 8) + tid;
  bool valid = ci < NCH;
  float e0=0,e1v=0,e2=0,e3=0,e4=0,e5=0;
  if (valid) {
    const float2* E = (const float2*)(ws + WS_F + ((long)row * NCH + ci) * 6);
    float2 p0 = E[0], p1 = E[1], p2 = E[2];
    e0=p0.x; e1v=p0.y; e2=p1.x; e3=p1.y; e4=p2.x; e5=p2.y;
  }
  __syncthreads();                                 // smat + audio resident

  // wave 0: exclusive row offset O = inclusive B-scan of AG[0..jb)  (B = W^256)
  if (wib == 0 && jb > 0) {
    float v6s[6];
    #pragma unroll
    for (int i = 0; i < 6; i++) v6s[i] = ag[i];
    #pragma unroll
    for (int k = 0; k < 6; k++) {
      int d = 1 << k;
      float u[6];
      #pragma unroll
      for (int i = 0; i < 6; i++) u[i] = __shfl_up(v6s[i], d, 64);
      float nv[6];
      MV6(nv, smat + (8 + k) * 36, u, v6s);        // B^(2^k)
      #pragma unroll
      for (int i = 0; i < 6; i++) v6s[i] = (lane >= d) ? nv[i] : v6s[i];
    }
    if (lane == jb - 1) {
      #pragma unroll
      for (int i = 0; i < 6; i++) sO[i] = v6s[i];
    }
  }
  __syncthreads();                                 // sO ready

  if (valid) {
    LOAD_COEFS(scoef);
    // absolute entry = rel_entry + W^tid * O_block
    float m[6];
    #pragma unroll
    for (int i = 0; i < 6; i++) m[i] = sO[i];
    float z6[6] = {0,0,0,0,0,0};
    #pragma unroll
    for (int k = 0; k < 8; k++) {
      if ((tid >> k) & 1) {
        float nm[6];
        MV6(nm, smat + k*36, m, z6);
        #pragma unroll
        for (int i = 0; i < 6; i++) m[i] = nm[i];
      }
    }
    float s11=e0+m[0], s21=e1v+m[1], s12=e2+m[2], s22=e3+m[3], s13=e4+m[4], s23=e5+m[5];
    int n4 = (ci == NCH - 1) ? 2 : 8;
    float* rowp = slab + (lane << 5);
    int xr = lane & 7;
    float y3;
    if (n4 == 8) {
      #pragma unroll
      for (int j4 = 0; j4 < 8; j4++) {
        float* p = rowp + ((j4 ^ xr) << 2);
        float4 v = *(const float4*)p;
        float4 o;
        CASCADE_STEP(v.x); o.x = y3;
        CASCADE_STEP(v.y); o.y = y3;
        CASCADE_STEP(v.z); o.z = y3;
        CASCADE_STEP(v.w); o.w = y3;
        *(float4*)p = o;
      }
    } else {
      for (int j4 = 0; j4 < 2; j4++) {
        float* p = rowp + ((j4 ^ xr) << 2);
        float4 v = *(const float4*)p;
        float4 o;
        CASCADE_STEP(v.x); o.x = y3;
        CASCADE_STEP(v.y); o.y = y3;
        CASCADE_STEP(v.z); o.z = y3;
        CASCADE_STEP(v.w); o.w = y3;
        *(float4*)p = o;
      }
    }
  }
  __syncthreads();
  float4* yp = (float4*)(y + rowbase + s0);
  if (span4 == 512) {
    #pragma unroll
    for (int i = 0; i < 8; i++) {
      int g = (i << 6) + lane;
      int s = (g & ~7) | ((g & 7) ^ ((g >> 3) & 7));
      yp[g] = *(const float4*)(slab + (s << 2));
    }
  } else {
    #pragma unroll
    for (int i = 0; i < 8; i++) {
      int g = (i << 6) + lane;
      int s = (g & ~7) | ((g & 7) ^ ((g >> 3) & 7));
      if (g < span4) yp[g] = *(const float4*)(slab + (s << 2));
    }
  }
}

extern "C" void kernel_launch(void* const* d_in, const int* in_sizes, int n_in,
                              void* d_out, int out_size, void* d_ws, size_t ws_size,
                              hipStream_t stream) {
  const float* audio = (const float*)d_in[0];
  const float* qs    = (const float*)d_in[1];
  const float* gains = (const float*)d_in[2];
  float* out = (float*)d_out;
  float* ws  = (float*)d_ws;

  hipLaunchKernelGGL(kA_scan, dim3(NBLK), dim3(256), 0, stream, audio, qs, gains, ws);
  hipLaunchKernelGGL(kC_emit, dim3(NBLK), dim3(256), 0, stream, audio, qs, gains, out, ws);
}